// Round 2
// baseline (2054.187 us; speedup 1.0000x reference)
//
#include <hip/hip_runtime.h>
#include <math.h>

constexpr int S_ = 2048, H_ = 1024, NH_ = 16, NKV_ = 4, D_ = 64;
constexpr int QKV_ = (NH_ + 2 * NKV_) * D_;  // 1536
constexpr int E_ = 8, F_ = 1024;
constexpr float EPS_ = 1e-5f, ALPHA_ = 1.702f, LIMIT_ = 7.0f;

// ---------------- fused add + RMSNorm ----------------
__global__ __launch_bounds__(256) void k_norm(const float* __restrict__ x,
                                              const float* __restrict__ add,
                                              const float* __restrict__ w,
                                              float* __restrict__ sum_out,
                                              float* __restrict__ nrm_out) {
  int t = blockIdx.x, tid = threadIdx.x;
  int lane = tid & 63, wid = tid >> 6;
  float v[4];
  float ss = 0.f;
#pragma unroll
  for (int i = 0; i < 4; i++) {
    int c = i * 256 + tid;
    float a = x[(size_t)t * H_ + c];
    if (add) a += add[(size_t)t * H_ + c];
    v[i] = a;
    ss += a * a;
  }
#pragma unroll
  for (int off = 32; off > 0; off >>= 1) ss += __shfl_xor(ss, off);
  __shared__ float red[4];
  __shared__ float scsh;
  if (lane == 0) red[wid] = ss;
  __syncthreads();
  if (tid == 0) scsh = rsqrtf((red[0] + red[1] + red[2] + red[3]) * (1.f / H_) + EPS_);
  __syncthreads();
  float sc = scsh;
#pragma unroll
  for (int i = 0; i < 4; i++) {
    int c = i * 256 + tid;
    if (sum_out) sum_out[(size_t)t * H_ + c] = v[i];
    nrm_out[(size_t)t * H_ + c] = v[i] * sc * w[c];
  }
}

// ---------------- generic fp32 GEMM tile: C[128 x 64] = A_gather @ B^T ----------------
// rows: shared array of 128 global row indices into A (-1 = invalid -> zeros)
__device__ __forceinline__ void gemm_body(const float* __restrict__ A, int lda,
                                          const int* rows,
                                          const float* __restrict__ B, int ldb,
                                          int n0, int K, float acc[8][4]) {
  __shared__ float As[128][17];
  __shared__ float Bs[64][17];
  const int tid = threadIdx.x;
  const int ty = tid >> 4, tx = tid & 15;
  for (int kt = 0; kt < K; kt += 16) {
#pragma unroll
    for (int i = 0; i < 8; i++) {
      int f = i * 256 + tid;
      int rr = f >> 4, kk = f & 15;
      int gr = rows[rr];
      As[rr][kk] = (gr >= 0) ? A[(size_t)gr * lda + kt + kk] : 0.f;
    }
#pragma unroll
    for (int i = 0; i < 4; i++) {
      int f = i * 256 + tid;
      int rr = f >> 4, kk = f & 15;
      Bs[rr][kk] = B[(size_t)(n0 + rr) * ldb + kt + kk];
    }
    __syncthreads();
#pragma unroll
    for (int k = 0; k < 16; k++) {
      float a[8], b[4];
#pragma unroll
      for (int i = 0; i < 8; i++) a[i] = As[ty * 8 + i][k];
#pragma unroll
      for (int j = 0; j < 4; j++) b[j] = Bs[tx * 4 + j][k];
#pragma unroll
      for (int i = 0; i < 8; i++)
#pragma unroll
        for (int j = 0; j < 4; j++) acc[i][j] += a[i] * b[j];
    }
    __syncthreads();
  }
}

// ---------------- QKV projection ----------------
__global__ __launch_bounds__(256) void k_gemm_qkv(const float* __restrict__ A,
                                                  const float* __restrict__ W,
                                                  const float* __restrict__ b,
                                                  float* __restrict__ out) {
  __shared__ int rows[128];
  int m0 = blockIdx.y * 128, n0 = blockIdx.x * 64;
  int tid = threadIdx.x;
  if (tid < 128) rows[tid] = m0 + tid;
  __syncthreads();
  float acc[8][4];
#pragma unroll
  for (int i = 0; i < 8; i++)
#pragma unroll
    for (int j = 0; j < 4; j++) acc[i][j] = 0.f;
  gemm_body(A, H_, rows, W, H_, n0, H_, acc);
  int ty = tid >> 4, tx = tid & 15;
#pragma unroll
  for (int i = 0; i < 8; i++)
#pragma unroll
    for (int j = 0; j < 4; j++) {
      int cc = n0 + tx * 4 + j;
      out[(size_t)(m0 + ty * 8 + i) * QKV_ + cc] = acc[i][j] + b[cc];
    }
}

// ---------------- O projection + bias + residual -> res2 ----------------
__global__ __launch_bounds__(256) void k_gemm_o(const float* __restrict__ A,
                                                const float* __restrict__ W,
                                                const float* __restrict__ b,
                                                const float* __restrict__ res1,
                                                float* __restrict__ res2) {
  __shared__ int rows[128];
  int m0 = blockIdx.y * 128, n0 = blockIdx.x * 64;
  int tid = threadIdx.x;
  if (tid < 128) rows[tid] = m0 + tid;
  __syncthreads();
  float acc[8][4];
#pragma unroll
  for (int i = 0; i < 8; i++)
#pragma unroll
    for (int j = 0; j < 4; j++) acc[i][j] = 0.f;
  gemm_body(A, H_, rows, W, H_, n0, H_, acc);
  int ty = tid >> 4, tx = tid & 15;
#pragma unroll
  for (int i = 0; i < 8; i++)
#pragma unroll
    for (int j = 0; j < 4; j++) {
      int rr = m0 + ty * 8 + i, cc = n0 + tx * 4 + j;
      res2[(size_t)rr * H_ + cc] = acc[i][j] + b[cc] + res1[(size_t)rr * H_ + cc];
    }
}

// ---------------- RoPE (in-place on q and k) ----------------
__global__ void k_rope(float* __restrict__ qkv, const int* __restrict__ positions) {
  int idx = blockIdx.x * 256 + threadIdx.x;  // S * 20 heads * 32 pairs
  int i = idx & 31;
  int hd = (idx >> 5) % 20;
  int t = idx / (20 * 32);
  float* base = qkv + (size_t)t * QKV_ + (hd < NH_ ? hd * D_ : NH_ * D_ + (hd - NH_) * D_);
  float pos = (float)positions[t];
  float invf = powf(10000.f, -(float)i * (1.f / 32.f));
  float ang = pos * invf;
  float sn, cs;
  sincosf(ang, &sn, &cs);
  float x1 = base[i], x2 = base[i + 32];
  base[i] = x1 * cs - x2 * sn;
  base[i + 32] = x2 * cs + x1 * sn;
}

// ---------------- causal GQA attention with sink (flash-style) ----------------
__global__ __launch_bounds__(256) void k_attn(const float* __restrict__ qkv,
                                              const float* __restrict__ sinks,
                                              float* __restrict__ attn) {
  int h = blockIdx.y;
  int qbase = blockIdx.x * 4;
  int tid = threadIdx.x, wid = tid >> 6, lane = tid & 63;
  int kvh = h >> 2;
  __shared__ float qs[4][68];
  __shared__ float Ks[64][68];
  __shared__ float Vs[64][68];
  __shared__ float ps[4][64];
  {
    int rq = tid >> 6, c = tid & 63;
    qs[rq][c] = qkv[(size_t)(qbase + rq) * QKV_ + h * D_ + c];
  }
  __syncthreads();
  int r = qbase + wid;
  float m = -INFINITY, l = 0.f, o = 0.f;
  int nch = qbase / 64 + 1;
  for (int ch = 0; ch < nch; ch++) {
#pragma unroll
    for (int i = 0; i < 16; i++) {
      int f = i * 256 + tid;
      int kr = f >> 6, kc = f & 63;
      size_t gb = (size_t)(ch * 64 + kr) * QKV_ + kvh * D_ + kc;
      Ks[kr][kc] = qkv[gb + NH_ * D_];
      Vs[kr][kc] = qkv[gb + NH_ * D_ + NKV_ * D_];
    }
    __syncthreads();
    int kj = ch * 64 + lane;
    float s = -INFINITY;
    if (kj <= r) {
      float a = 0.f;
#pragma unroll
      for (int d = 0; d < 64; d++) a += qs[wid][d] * Ks[lane][d];
      s = a * 0.125f;  // D^-0.5
    }
    float mc = s;
#pragma unroll
    for (int off = 32; off > 0; off >>= 1) mc = fmaxf(mc, __shfl_xor(mc, off));
    float mn = fmaxf(m, mc);
    float sf = expf(m - mn);
    float p = (kj <= r) ? expf(s - mn) : 0.f;
    float ls = p;
#pragma unroll
    for (int off = 32; off > 0; off >>= 1) ls += __shfl_xor(ls, off);
    l = l * sf + ls;
    m = mn;
    ps[wid][lane] = p;  // same-wave LDS: in-order, no barrier needed
    float ov = 0.f;
#pragma unroll
    for (int j = 0; j < 64; j++) ov += ps[wid][j] * Vs[j][lane];
    o = o * sf + ov;
    __syncthreads();
  }
  float snk = sinks[h];
  float mf = fmaxf(m, snk);
  float li = 1.f / (l * expf(m - mf) + expf(snk - mf));
  o = o * expf(m - mf) * li;
  attn[(size_t)r * H_ + h * D_ + lane] = o;
}

// ---------------- router: logits, top-2, per-expert gather lists ----------------
__global__ __launch_bounds__(64) void k_router(const float* __restrict__ h2,
                                               const float* __restrict__ rw,
                                               const float* __restrict__ rb,
                                               int* __restrict__ counts,
                                               int* __restrict__ perm,
                                               float* __restrict__ pw) {
  int t = blockIdx.x, lane = threadIdx.x;
  float acc[E_];
#pragma unroll
  for (int e = 0; e < E_; e++) acc[e] = 0.f;
  for (int i = 0; i < 16; i++) {
    float x = h2[(size_t)t * H_ + i * 64 + lane];
#pragma unroll
    for (int e = 0; e < E_; e++) acc[e] += x * rw[e * H_ + i * 64 + lane];
  }
#pragma unroll
  for (int e = 0; e < E_; e++) {
#pragma unroll
    for (int off = 32; off > 0; off >>= 1) acc[e] += __shfl_xor(acc[e], off);
  }
  if (lane == 0) {
    float lg[E_];
#pragma unroll
    for (int e = 0; e < E_; e++) lg[e] = acc[e] + rb[e];
    int i0 = 0;
    float v0 = lg[0];
    for (int e = 1; e < E_; e++)
      if (lg[e] > v0) { v0 = lg[e]; i0 = e; }
    int i1 = -1;
    float v1 = -INFINITY;
    for (int e = 0; e < E_; e++) {
      if (e == i0) continue;
      if (lg[e] > v1) { v1 = lg[e]; i1 = e; }
    }
    float ex = expf(v1 - v0);
    float w0 = 1.f / (1.f + ex);
    float w1 = ex * w0;
    int p0 = atomicAdd(&counts[i0], 1);
    perm[i0 * S_ + p0] = t * 2;
    pw[i0 * S_ + p0] = w0;
    int p1 = atomicAdd(&counts[i1], 1);
    perm[i1 * S_ + p1] = t * 2 + 1;
    pw[i1 * S_ + p1] = w1;
  }
}

// ---------------- MoE gate_up + SwiGLU -> actbuf ----------------
__global__ __launch_bounds__(256) void k_gemm_gu(const float* __restrict__ h2,
                                                 const float* __restrict__ W,
                                                 const float* __restrict__ b,
                                                 const int* __restrict__ counts,
                                                 const int* __restrict__ perm,
                                                 float* __restrict__ actbuf) {
  int e = blockIdx.z;
  int cnt = counts[e];
  int m0 = blockIdx.y * 128;
  if (m0 >= cnt) return;
  int n0 = blockIdx.x * 64;
  __shared__ int rows[128];
  __shared__ int slots[128];
  int tid = threadIdx.x;
  if (tid < 128) {
    int idx = m0 + tid;
    int p = (idx < cnt) ? perm[e * S_ + idx] : -1;
    slots[tid] = p;
    rows[tid] = (p >= 0) ? (p >> 1) : -1;
  }
  __syncthreads();
  float acc[8][4];
#pragma unroll
  for (int i = 0; i < 8; i++)
#pragma unroll
    for (int j = 0; j < 4; j++) acc[i][j] = 0.f;
  gemm_body(h2, H_, rows, W + (size_t)e * 2 * F_ * H_, H_, n0, H_, acc);
  int ty = tid >> 4, tx = tid & 15;
  const float* eb = b + (size_t)e * 2 * F_;
#pragma unroll
  for (int i = 0; i < 8; i++) {
    int rr = ty * 8 + i;
    int p = slots[rr];
    if (p < 0) continue;
#pragma unroll
    for (int j = 0; j < 4; j += 2) {
      int cc = n0 + tx * 4 + j;  // even: gate, odd: up
      float g = acc[i][j] + eb[cc];
      float u = acc[i][j + 1] + eb[cc + 1];
      g = fminf(g, LIMIT_);
      u = fminf(fmaxf(u, -LIMIT_), LIMIT_);
      float glu = g / (1.f + expf(-g * ALPHA_));
      actbuf[(size_t)p * F_ + (cc >> 1)] = (u + 1.f) * glu;
    }
  }
}

// ---------------- MoE down proj + weighted scatter ----------------
__global__ __launch_bounds__(256) void k_gemm_down(const float* __restrict__ actbuf,
                                                   const float* __restrict__ W,
                                                   const float* __restrict__ b,
                                                   const int* __restrict__ counts,
                                                   const int* __restrict__ perm,
                                                   const float* __restrict__ pw,
                                                   float* __restrict__ moe) {
  int e = blockIdx.z;
  int cnt = counts[e];
  int m0 = blockIdx.y * 128;
  if (m0 >= cnt) return;
  int n0 = blockIdx.x * 64;
  __shared__ int rows[128];
  __shared__ float wts[128];
  int tid = threadIdx.x;
  if (tid < 128) {
    int idx = m0 + tid;
    int p = -1;
    float w = 0.f;
    if (idx < cnt) {
      p = perm[e * S_ + idx];
      w = pw[e * S_ + idx];
    }
    rows[tid] = p;  // actbuf is indexed by slot id directly
    wts[tid] = w;
  }
  __syncthreads();
  float acc[8][4];
#pragma unroll
  for (int i = 0; i < 8; i++)
#pragma unroll
    for (int j = 0; j < 4; j++) acc[i][j] = 0.f;
  gemm_body(actbuf, F_, rows, W + (size_t)e * H_ * F_, F_, n0, F_, acc);
  int ty = tid >> 4, tx = tid & 15;
#pragma unroll
  for (int i = 0; i < 8; i++) {
    int rr = ty * 8 + i;
    int p = rows[rr];
    if (p < 0) continue;
    float w = wts[rr];
#pragma unroll
    for (int j = 0; j < 4; j++) {
      int cc = n0 + tx * 4 + j;
      float val = (acc[i][j] + b[(size_t)e * H_ + cc]) * w;
      atomicAdd(&moe[(size_t)(p >> 1) * H_ + cc], val);
    }
  }
}

extern "C" void kernel_launch(void* const* d_in, const int* in_sizes, int n_in,
                              void* d_out, int out_size, void* d_ws, size_t ws_size,
                              hipStream_t stream) {
  (void)in_sizes; (void)n_in; (void)out_size; (void)ws_size;
  const float* hidden   = (const float*)d_in[0];
  const float* residual = (const float*)d_in[1];
  const int*   positions= (const int*)d_in[2];
  const float* ln1_w    = (const float*)d_in[3];
  const float* ln2_w    = (const float*)d_in[4];
  const float* qkv_w    = (const float*)d_in[5];
  const float* qkv_b    = (const float*)d_in[6];
  const float* sinks    = (const float*)d_in[7];
  const float* o_w      = (const float*)d_in[8];
  const float* o_b      = (const float*)d_in[9];
  const float* router_w = (const float*)d_in[10];
  const float* router_b = (const float*)d_in[11];
  const float* gu_w     = (const float*)d_in[12];
  const float* gu_b     = (const float*)d_in[13];
  const float* dn_w     = (const float*)d_in[14];
  const float* dn_b     = (const float*)d_in[15];

  float* out_moe = (float*)d_out;
  float* res2 = (float*)d_out + (size_t)S_ * H_;

  char* ws = (char*)d_ws;
  size_t off = 0;
  auto alloc = [&](size_t bytes) {
    void* p = ws + off;
    off = (off + bytes + 255) & ~(size_t)255;
    return p;
  };
  int*   counts = (int*)alloc(E_ * sizeof(int));
  int*   perm   = (int*)alloc((size_t)E_ * S_ * sizeof(int));
  float* pw     = (float*)alloc((size_t)E_ * S_ * sizeof(float));
  float* res1   = (float*)alloc((size_t)S_ * H_ * 4);
  float* hbuf   = (float*)alloc((size_t)S_ * H_ * 4);
  float* qkv    = (float*)alloc((size_t)S_ * QKV_ * 4);
  float* attn   = (float*)alloc((size_t)S_ * H_ * 4);
  float* h2     = (float*)alloc((size_t)S_ * H_ * 4);
  float* actbuf = (float*)alloc((size_t)2 * S_ * F_ * 4);

  hipMemsetAsync(counts, 0, E_ * sizeof(int), stream);
  hipMemsetAsync(out_moe, 0, (size_t)S_ * H_ * 4, stream);

  k_norm<<<S_, 256, 0, stream>>>(hidden, residual, ln1_w, res1, hbuf);
  k_gemm_qkv<<<dim3(QKV_ / 64, S_ / 128), 256, 0, stream>>>(hbuf, qkv_w, qkv_b, qkv);
  k_rope<<<(S_ * 20 * 32) / 256, 256, 0, stream>>>(qkv, positions);
  k_attn<<<dim3(S_ / 4, NH_), 256, 0, stream>>>(qkv, sinks, attn);
  k_gemm_o<<<dim3(H_ / 64, S_ / 128), 256, 0, stream>>>(attn, o_w, o_b, res1, res2);
  k_norm<<<S_, 256, 0, stream>>>(res2, nullptr, ln2_w, nullptr, h2);
  k_router<<<S_, 64, 0, stream>>>(h2, router_w, router_b, counts, perm, pw);
  k_gemm_gu<<<dim3(2 * F_ / 64, S_ / 128, E_), 256, 0, stream>>>(h2, gu_w, gu_b, counts, perm, actbuf);
  k_gemm_down<<<dim3(H_ / 64, S_ / 128, E_), 256, 0, stream>>>(actbuf, dn_w, dn_b, counts, perm, pw, out_moe);
}

// Round 4
// 978.414 us; speedup vs baseline: 2.0995x; 2.0995x over previous
//
#include <hip/hip_runtime.h>
#include <math.h>

constexpr int S_ = 2048, H_ = 1024, NH_ = 16, NKV_ = 4, D_ = 64;
constexpr int QKV_ = (NH_ + 2 * NKV_) * D_;  // 1536
constexpr int E_ = 8, F_ = 1024;
constexpr float EPS_ = 1e-5f, ALPHA_ = 1.702f, LIMIT_ = 7.0f;

typedef __attribute__((ext_vector_type(8))) short short8;
typedef __attribute__((ext_vector_type(4))) float f32x4;

__device__ __forceinline__ short f2bf(float f) {
  union { float f; unsigned u; } v; v.f = f;
  unsigned r = v.u + 0x7fffu + ((v.u >> 16) & 1u);
  return (short)(r >> 16);
}

__device__ __forceinline__ void gload_lds16(const void* g, void* l) {
  __builtin_amdgcn_global_load_lds((const __attribute__((address_space(1))) void*)g,
                                   (__attribute__((address_space(3))) void*)l, 16, 0, 0);
}

// ---------------- fp32 -> bf16 convert ----------------
__global__ __launch_bounds__(256) void k_cvt(const float* __restrict__ in,
                                             short* __restrict__ out, int n4) {
  int i = blockIdx.x * 256 + threadIdx.x;
  int stride = gridDim.x * 256;
  for (; i < n4; i += stride) {
    float4 v = ((const float4*)in)[i];
    short4 o;
    o.x = f2bf(v.x); o.y = f2bf(v.y); o.z = f2bf(v.z); o.w = f2bf(v.w);
    ((short4*)out)[i] = o;
  }
}

// ---------------- fused add + RMSNorm (fp32 out and/or bf16 out) ----------------
__global__ __launch_bounds__(256) void k_norm(const float* __restrict__ x,
                                              const float* __restrict__ add,
                                              const float* __restrict__ w,
                                              float* __restrict__ sum_out,
                                              float* __restrict__ nrm_out,
                                              short* __restrict__ nrm_bf) {
  int t = blockIdx.x, tid = threadIdx.x;
  int lane = tid & 63, wid = tid >> 6;
  float v[4];
  float ss = 0.f;
#pragma unroll
  for (int i = 0; i < 4; i++) {
    int c = i * 256 + tid;
    float a = x[(size_t)t * H_ + c];
    if (add) a += add[(size_t)t * H_ + c];
    v[i] = a;
    ss += a * a;
  }
#pragma unroll
  for (int off = 32; off > 0; off >>= 1) ss += __shfl_xor(ss, off);
  __shared__ float red[4];
  __shared__ float scsh;
  if (lane == 0) red[wid] = ss;
  __syncthreads();
  if (tid == 0) scsh = rsqrtf((red[0] + red[1] + red[2] + red[3]) * (1.f / H_) + EPS_);
  __syncthreads();
  float sc = scsh;
#pragma unroll
  for (int i = 0; i < 4; i++) {
    int c = i * 256 + tid;
    float nv = v[i] * sc * w[c];
    if (sum_out) sum_out[(size_t)t * H_ + c] = v[i];
    if (nrm_out) nrm_out[(size_t)t * H_ + c] = nv;
    if (nrm_bf)  nrm_bf[(size_t)t * H_ + c] = f2bf(nv);
  }
}

// ---------------- bf16 MFMA GEMM core: C[128x128] = A_gather[128xK] @ B[:,K]^T --------
__device__ __forceinline__ void mfma_core(const short* __restrict__ A, int lda,
                                          const short* __restrict__ B, int ldb,
                                          int n0, int K,
                                          const int* rows_sh, char* smem,
                                          f32x4 acc[4][4]) {
  const int tid = threadIdx.x;
  const int wid = tid >> 6, lane = tid & 63;
  const int wr = wid >> 1, wc = wid & 1;
  const int fl = lane & 15, fh = lane >> 4;
  const short* src[4];
  unsigned lofs[4];
  {
    const int kofs = (lane & 3) * 8;
    const int r4 = lane >> 2;
#pragma unroll
    for (int j = 0; j < 4; j++) {
      int inst = (wid & 1) * 4 + j;
      int row = inst * 16 + r4;
      if (wid < 2) {
        src[j] = A + (size_t)rows_sh[row] * lda + kofs;
        lofs[j] = inst * 1024u;
      } else {
        src[j] = B + (size_t)(n0 + row) * ldb + kofs;
        lofs[j] = 8192u + inst * 1024u;
      }
    }
  }
  char* As = smem;
  char* Bs = smem + 8192;
  const int abase = (wr * 64 + fl) * 64 + fh * 16;
  const int bbase = (wc * 64 + fl) * 64 + fh * 16;
  for (int kt = 0; kt < K; kt += 32) {
#pragma unroll
    for (int j = 0; j < 4; j++) gload_lds16(src[j] + kt, smem + lofs[j]);
    asm volatile("s_waitcnt vmcnt(0)" ::: "memory");
    __syncthreads();
    short8 a[4], b[4];
#pragma unroll
    for (int mi = 0; mi < 4; mi++) a[mi] = *(const short8*)(As + abase + mi * 1024);
#pragma unroll
    for (int nj = 0; nj < 4; nj++) b[nj] = *(const short8*)(Bs + bbase + nj * 1024);
#pragma unroll
    for (int mi = 0; mi < 4; mi++)
#pragma unroll
      for (int nj = 0; nj < 4; nj++)
        acc[mi][nj] = __builtin_amdgcn_mfma_f32_16x16x32_bf16(a[mi], b[nj], acc[mi][nj], 0, 0, 0);
    __syncthreads();
  }
}

// ---------------- QKV projection ----------------
__global__ __launch_bounds__(256) void k_mfma_qkv(const short* __restrict__ A,
                                                  const short* __restrict__ W,
                                                  const float* __restrict__ bias,
                                                  float* __restrict__ out) {
  __shared__ __align__(16) char smem[16384];
  __shared__ int rows_sh[128];
  int m0 = blockIdx.y * 128, n0 = blockIdx.x * 128;
  int tid = threadIdx.x;
  if (tid < 128) rows_sh[tid] = m0 + tid;
  __syncthreads();
  f32x4 acc[4][4] = {};
  mfma_core(A, H_, W, H_, n0, H_, rows_sh, smem, acc);
  const int wid = tid >> 6, lane = tid & 63;
  const int wr = wid >> 1, wc = wid & 1, fl = lane & 15, fh = lane >> 4;
#pragma unroll
  for (int mi = 0; mi < 4; mi++)
#pragma unroll
    for (int nj = 0; nj < 4; nj++) {
      int c = n0 + wc * 64 + nj * 16 + fl;
      float bv = bias[c];
#pragma unroll
      for (int j = 0; j < 4; j++) {
        int r = m0 + wr * 64 + mi * 16 + fh * 4 + j;
        out[(size_t)r * QKV_ + c] = acc[mi][nj][j] + bv;
      }
    }
}

// ---------------- O projection + bias + residual -> res2 ----------------
__global__ __launch_bounds__(256) void k_mfma_o(const short* __restrict__ A,
                                                const short* __restrict__ W,
                                                const float* __restrict__ bias,
                                                const float* __restrict__ res1,
                                                float* __restrict__ res2) {
  __shared__ __align__(16) char smem[16384];
  __shared__ int rows_sh[128];
  int m0 = blockIdx.y * 128, n0 = blockIdx.x * 128;
  int tid = threadIdx.x;
  if (tid < 128) rows_sh[tid] = m0 + tid;
  __syncthreads();
  f32x4 acc[4][4] = {};
  mfma_core(A, H_, W, H_, n0, H_, rows_sh, smem, acc);
  const int wid = tid >> 6, lane = tid & 63;
  const int wr = wid >> 1, wc = wid & 1, fl = lane & 15, fh = lane >> 4;
#pragma unroll
  for (int mi = 0; mi < 4; mi++)
#pragma unroll
    for (int nj = 0; nj < 4; nj++) {
      int c = n0 + wc * 64 + nj * 16 + fl;
      float bv = bias[c];
#pragma unroll
      for (int j = 0; j < 4; j++) {
        int r = m0 + wr * 64 + mi * 16 + fh * 4 + j;
        res2[(size_t)r * H_ + c] = acc[mi][nj][j] + bv + res1[(size_t)r * H_ + c];
      }
    }
}

// ---------------- RoPE (in-place on q and k, fp32 qkv) ----------------
__global__ void k_rope(float* __restrict__ qkv, const int* __restrict__ positions) {
  int idx = blockIdx.x * 256 + threadIdx.x;
  int i = idx & 31;
  int hd = (idx >> 5) % 20;
  int t = idx / (20 * 32);
  float* base = qkv + (size_t)t * QKV_ + (hd < NH_ ? hd * D_ : NH_ * D_ + (hd - NH_) * D_);
  float pos = (float)positions[t];
  float invf = powf(10000.f, -(float)i * (1.f / 32.f));
  float ang = pos * invf;
  float sn, cs;
  sincosf(ang, &sn, &cs);
  float x1 = base[i], x2 = base[i + 32];
  base[i] = x1 * cs - x2 * sn;
  base[i + 32] = x2 * cs + x1 * sn;
}

// ---------------- causal GQA attention with sink (fp32), bf16 out ----------------
__global__ __launch_bounds__(256) void k_attn(const float* __restrict__ qkv,
                                              const float* __restrict__ sinks,
                                              short* __restrict__ attnb) {
  int h = blockIdx.y;
  int qbase = blockIdx.x * 4;
  int tid = threadIdx.x, wid = tid >> 6, lane = tid & 63;
  int kvh = h >> 2;
  __shared__ float qs[4][68];
  __shared__ float Ks[64][68];
  __shared__ float Vs[64][68];
  __shared__ float ps[4][64];
  {
    int rq = tid >> 6, c = tid & 63;
    qs[rq][c] = qkv[(size_t)(qbase + rq) * QKV_ + h * D_ + c];
  }
  __syncthreads();
  int r = qbase + wid;
  float m = -INFINITY, l = 0.f, o = 0.f;
  int nch = qbase / 64 + 1;
  for (int ch = 0; ch < nch; ch++) {
#pragma unroll
    for (int i = 0; i < 16; i++) {
      int f = i * 256 + tid;
      int kr = f >> 6, kc = f & 63;
      size_t gb = (size_t)(ch * 64 + kr) * QKV_ + kvh * D_ + kc;
      Ks[kr][kc] = qkv[gb + NH_ * D_];
      Vs[kr][kc] = qkv[gb + NH_ * D_ + NKV_ * D_];
    }
    __syncthreads();
    int kj = ch * 64 + lane;
    float s = -INFINITY;
    if (kj <= r) {
      float a = 0.f;
#pragma unroll
      for (int d = 0; d < 64; d++) a += qs[wid][d] * Ks[lane][d];
      s = a * 0.125f;
    }
    float mc = s;
#pragma unroll
    for (int off = 32; off > 0; off >>= 1) mc = fmaxf(mc, __shfl_xor(mc, off));
    float mn = fmaxf(m, mc);
    float sf = expf(m - mn);
    float p = (kj <= r) ? expf(s - mn) : 0.f;
    float ls = p;
#pragma unroll
    for (int off = 32; off > 0; off >>= 1) ls += __shfl_xor(ls, off);
    l = l * sf + ls;
    m = mn;
    ps[wid][lane] = p;
    float ov = 0.f;
#pragma unroll
    for (int j = 0; j < 64; j++) ov += ps[wid][j] * Vs[j][lane];
    o = o * sf + ov;
    __syncthreads();
  }
  float snk = sinks[h];
  float mf = fmaxf(m, snk);
  float li = 1.f / (l * expf(m - mf) + expf(snk - mf));
  o = o * expf(m - mf) * li;
  attnb[(size_t)r * H_ + h * D_ + lane] = f2bf(o);
}

// ---------------- router (fp32 h2) ----------------
__global__ __launch_bounds__(64) void k_router(const float* __restrict__ h2,
                                               const float* __restrict__ rw,
                                               const float* __restrict__ rb,
                                               int* __restrict__ counts,
                                               int* __restrict__ perm,
                                               float* __restrict__ pw) {
  int t = blockIdx.x, lane = threadIdx.x;
  float acc[E_];
#pragma unroll
  for (int e = 0; e < E_; e++) acc[e] = 0.f;
  for (int i = 0; i < 16; i++) {
    float x = h2[(size_t)t * H_ + i * 64 + lane];
#pragma unroll
    for (int e = 0; e < E_; e++) acc[e] += x * rw[e * H_ + i * 64 + lane];
  }
#pragma unroll
  for (int e = 0; e < E_; e++) {
#pragma unroll
    for (int off = 32; off > 0; off >>= 1) acc[e] += __shfl_xor(acc[e], off);
  }
  if (lane == 0) {
    float lg[E_];
#pragma unroll
    for (int e = 0; e < E_; e++) lg[e] = acc[e] + rb[e];
    int i0 = 0;
    float v0 = lg[0];
    for (int e = 1; e < E_; e++)
      if (lg[e] > v0) { v0 = lg[e]; i0 = e; }
    int i1 = -1;
    float v1 = -INFINITY;
    for (int e = 0; e < E_; e++) {
      if (e == i0) continue;
      if (lg[e] > v1) { v1 = lg[e]; i1 = e; }
    }
    float ex = expf(v1 - v0);
    float w0 = 1.f / (1.f + ex);
    float w1 = ex * w0;
    int p0 = atomicAdd(&counts[i0], 1);
    if (p0 < S_) { perm[i0 * S_ + p0] = t * 2;     pw[i0 * S_ + p0] = w0; }
    int p1 = atomicAdd(&counts[i1], 1);
    if (p1 < S_) { perm[i1 * S_ + p1] = t * 2 + 1; pw[i1 * S_ + p1] = w1; }
  }
}

// ---------------- MoE gate_up + SwiGLU -> actbuf (bf16, slot-indexed) ----------------
__global__ __launch_bounds__(256) void k_mfma_gu(const short* __restrict__ h2b,
                                                 const short* __restrict__ W,
                                                 const float* __restrict__ gu_b,
                                                 const int* __restrict__ counts,
                                                 const int* __restrict__ perm,
                                                 short* __restrict__ actb) {
  int e = blockIdx.z;
  int cnt = counts[e];
  int m0 = blockIdx.y * 128;
  if (m0 >= cnt) return;
  int n0 = blockIdx.x * 128;
  __shared__ __align__(16) char smem[16384];
  __shared__ int rows_sh[128];
  __shared__ int slots_sh[128];
  int tid = threadIdx.x;
  if (tid < 128) {
    int idx = m0 + tid;
    int p = (idx < cnt) ? perm[e * S_ + idx] : -1;
    slots_sh[tid] = p;
    rows_sh[tid] = (p >= 0) ? (p >> 1) : 0;
  }
  __syncthreads();
  f32x4 acc[4][4] = {};
  mfma_core(h2b, H_, W + (size_t)e * 2 * F_ * H_, H_, n0, H_, rows_sh, smem, acc);
  const int wid = tid >> 6, lane = tid & 63;
  const int wr = wid >> 1, wc = wid & 1, fl = lane & 15, fh = lane >> 4;
  const float* gub = gu_b + (size_t)e * 2 * F_;
#pragma unroll
  for (int mi = 0; mi < 4; mi++)
#pragma unroll
    for (int nj = 0; nj < 4; nj++) {
      int c = n0 + wc * 64 + nj * 16 + fl;
      float bv = gub[c];
#pragma unroll
      for (int j = 0; j < 4; j++) {
        int r = wr * 64 + mi * 16 + fh * 4 + j;
        float v = acc[mi][nj][j] + bv;
        float other = __shfl_xor(v, 1);
        if (!(lane & 1)) {
          int slot = slots_sh[r];
          if (slot >= 0) {
            float g = fminf(v, LIMIT_);
            float u = fminf(fmaxf(other, -LIMIT_), LIMIT_);
            float a = (u + 1.f) * (g / (1.f + expf(-g * ALPHA_)));
            actb[(size_t)slot * F_ + (c >> 1)] = f2bf(a);
          }
        }
      }
    }
}

// ---------------- MoE down proj -> dnout (fp32, slot-indexed, weight applied) ---------
__global__ __launch_bounds__(256) void k_mfma_down(const short* __restrict__ actb,
                                                   const short* __restrict__ W,
                                                   const float* __restrict__ dn_b,
                                                   const int* __restrict__ counts,
                                                   const int* __restrict__ perm,
                                                   const float* __restrict__ pw,
                                                   float* __restrict__ dnout) {
  int e = blockIdx.z;
  int cnt = counts[e];
  int m0 = blockIdx.y * 128;
  if (m0 >= cnt) return;
  int n0 = blockIdx.x * 128;
  __shared__ __align__(16) char smem[16384];
  __shared__ int rows_sh[128];
  __shared__ float wts_sh[128];
  int tid = threadIdx.x;
  if (tid < 128) {
    int idx = m0 + tid;
    int p = 0;
    float w = 0.f;
    if (idx < cnt) { p = perm[e * S_ + idx]; w = pw[e * S_ + idx]; }
    rows_sh[tid] = p;  // actbuf is slot-indexed
    wts_sh[tid] = w;
  }
  __syncthreads();
  f32x4 acc[4][4] = {};
  mfma_core(actb, F_, W + (size_t)e * H_ * F_, F_, n0, F_, rows_sh, smem, acc);
  const int wid = tid >> 6, lane = tid & 63;
  const int wr = wid >> 1, wc = wid & 1, fl = lane & 15, fh = lane >> 4;
  const float* dnb = dn_b + (size_t)e * H_;
#pragma unroll
  for (int mi = 0; mi < 4; mi++)
#pragma unroll
    for (int nj = 0; nj < 4; nj++) {
      int c = n0 + wc * 64 + nj * 16 + fl;
      float bv = dnb[c];
#pragma unroll
      for (int j = 0; j < 4; j++) {
        int r = wr * 64 + mi * 16 + fh * 4 + j;
        if (m0 + r < cnt) {
          int slot = rows_sh[r];
          dnout[(size_t)slot * H_ + c] = (acc[mi][nj][j] + bv) * wts_sh[r];
        }
      }
    }
}

// ---------------- combine the two expert slots per token ----------------
__global__ __launch_bounds__(256) void k_combine(const float* __restrict__ dnout,
                                                 float* __restrict__ out) {
  int i = blockIdx.x * 256 + threadIdx.x;  // over S*H/4
  int t = i >> 8, c = i & 255;             // H/4 = 256
  const float4* a = (const float4*)dnout;
  float4 x = a[(size_t)(2 * t) * 256 + c];
  float4 y = a[(size_t)(2 * t + 1) * 256 + c];
  float4 o;
  o.x = x.x + y.x; o.y = x.y + y.y; o.z = x.z + y.z; o.w = x.w + y.w;
  ((float4*)out)[i] = o;
}

extern "C" void kernel_launch(void* const* d_in, const int* in_sizes, int n_in,
                              void* d_out, int out_size, void* d_ws, size_t ws_size,
                              hipStream_t stream) {
  (void)in_sizes; (void)n_in; (void)out_size; (void)ws_size;
  const float* hidden   = (const float*)d_in[0];
  const float* residual = (const float*)d_in[1];
  const int*   positions= (const int*)d_in[2];
  const float* ln1_w    = (const float*)d_in[3];
  const float* ln2_w    = (const float*)d_in[4];
  const float* qkv_w    = (const float*)d_in[5];
  const float* qkv_b    = (const float*)d_in[6];
  const float* sinks    = (const float*)d_in[7];
  const float* o_w      = (const float*)d_in[8];
  const float* o_b      = (const float*)d_in[9];
  const float* router_w = (const float*)d_in[10];
  const float* router_b = (const float*)d_in[11];
  const float* gu_w     = (const float*)d_in[12];
  const float* gu_b     = (const float*)d_in[13];
  const float* dn_w     = (const float*)d_in[14];
  const float* dn_b     = (const float*)d_in[15];

  float* out_moe = (float*)d_out;
  float* res2 = (float*)d_out + (size_t)S_ * H_;

  char* ws = (char*)d_ws;
  size_t off = 0;
  auto alloc = [&](size_t bytes) {
    void* p = ws + off;
    off = (off + bytes + 255) & ~(size_t)255;
    return p;
  };
  int*   counts  = (int*)alloc(E_ * sizeof(int));
  int*   perm    = (int*)alloc((size_t)E_ * S_ * sizeof(int));
  float* pw      = (float*)alloc((size_t)E_ * S_ * sizeof(float));
  float* res1    = (float*)alloc((size_t)S_ * H_ * 4);
  short* hbuf_b  = (short*)alloc((size_t)S_ * H_ * 2);
  float* qkv     = (float*)alloc((size_t)S_ * QKV_ * 4);
  short* attnb   = (short*)alloc((size_t)S_ * H_ * 2);
  float* h2      = (float*)alloc((size_t)S_ * H_ * 4);
  short* h2b     = (short*)alloc((size_t)S_ * H_ * 2);
  short* actb    = (short*)alloc((size_t)2 * S_ * F_ * 2);
  float* dnout   = (float*)alloc((size_t)2 * S_ * H_ * 4);
  short* qkv_wb  = (short*)alloc((size_t)QKV_ * H_ * 2);
  short* o_wb    = (short*)alloc((size_t)H_ * H_ * 2);
  short* gu_wb   = (short*)alloc((size_t)E_ * 2 * F_ * H_ * 2);
  short* dn_wb   = (short*)alloc((size_t)E_ * H_ * F_ * 2);

  hipMemsetAsync(counts, 0, E_ * sizeof(int), stream);

  k_cvt<<<1024, 256, 0, stream>>>(qkv_w, qkv_wb, QKV_ * H_ / 4);
  k_cvt<<<1024, 256, 0, stream>>>(o_w, o_wb, H_ * H_ / 4);
  k_cvt<<<2048, 256, 0, stream>>>(gu_w, gu_wb, E_ * 2 * F_ * H_ / 4);
  k_cvt<<<2048, 256, 0, stream>>>(dn_w, dn_wb, E_ * H_ * F_ / 4);

  k_norm<<<S_, 256, 0, stream>>>(hidden, residual, ln1_w, res1, nullptr, hbuf_b);
  k_mfma_qkv<<<dim3(QKV_ / 128, S_ / 128), 256, 0, stream>>>(hbuf_b, qkv_wb, qkv_b, qkv);
  k_rope<<<(S_ * 20 * 32) / 256, 256, 0, stream>>>(qkv, positions);
  k_attn<<<dim3(S_ / 4, NH_), 256, 0, stream>>>(qkv, sinks, attnb);
  k_mfma_o<<<dim3(H_ / 128, S_ / 128), 256, 0, stream>>>(attnb, o_wb, o_b, res1, res2);
  k_norm<<<S_, 256, 0, stream>>>(res2, nullptr, ln2_w, nullptr, h2, h2b);
  k_router<<<S_, 64, 0, stream>>>(h2, router_w, router_b, counts, perm, pw);
  k_mfma_gu<<<dim3(2 * F_ / 128, S_ / 128, E_), 256, 0, stream>>>(h2b, gu_wb, gu_b, counts, perm, actb);
  k_mfma_down<<<dim3(H_ / 128, S_ / 128, E_), 256, 0, stream>>>(actb, dn_wb, dn_b, counts, perm, pw, dnout);
  k_combine<<<(S_ * H_ / 4) / 256, 256, 0, stream>>>(dnout, out_moe);
}

// Round 5
// 451.292 us; speedup vs baseline: 4.5518x; 2.1680x over previous
//
#include <hip/hip_runtime.h>
#include <math.h>

constexpr int S_ = 2048, H_ = 1024, NH_ = 16, NKV_ = 4, D_ = 64;
constexpr int QKV_ = (NH_ + 2 * NKV_) * D_;  // 1536
constexpr int E_ = 8, F_ = 1024;
constexpr float EPS_ = 1e-5f, ALPHA_ = 1.702f, LIMIT_ = 7.0f;

typedef __attribute__((ext_vector_type(8))) short short8;
typedef __attribute__((ext_vector_type(4))) float f32x4;

__device__ __forceinline__ short f2bf(float f) {
  union { float f; unsigned u; } v; v.f = f;
  unsigned r = v.u + 0x7fffu + ((v.u >> 16) & 1u);
  return (short)(r >> 16);
}

__device__ __forceinline__ void gload_lds16(const void* g, void* l) {
  __builtin_amdgcn_global_load_lds((const __attribute__((address_space(1))) void*)g,
                                   (__attribute__((address_space(3))) void*)l, 16, 0, 0);
}

// ---------------- fp32 -> bf16 convert ----------------
__global__ __launch_bounds__(256) void k_cvt(const float* __restrict__ in,
                                             short* __restrict__ out, int n4) {
  int i = blockIdx.x * 256 + threadIdx.x;
  int stride = gridDim.x * 256;
  for (; i < n4; i += stride) {
    float4 v = ((const float4*)in)[i];
    short4 o;
    o.x = f2bf(v.x); o.y = f2bf(v.y); o.z = f2bf(v.z); o.w = f2bf(v.w);
    ((short4*)out)[i] = o;
  }
}

// ---------------- fused add + RMSNorm ----------------
__global__ __launch_bounds__(256) void k_norm(const float* __restrict__ x,
                                              const float* __restrict__ add,
                                              const float* __restrict__ w,
                                              float* __restrict__ sum_out,
                                              float* __restrict__ nrm_out,
                                              short* __restrict__ nrm_bf) {
  int t = blockIdx.x, tid = threadIdx.x;
  int lane = tid & 63, wid = tid >> 6;
  float v[4];
  float ss = 0.f;
#pragma unroll
  for (int i = 0; i < 4; i++) {
    int c = i * 256 + tid;
    float a = x[(size_t)t * H_ + c];
    if (add) a += add[(size_t)t * H_ + c];
    v[i] = a;
    ss += a * a;
  }
#pragma unroll
  for (int off = 32; off > 0; off >>= 1) ss += __shfl_xor(ss, off);
  __shared__ float red[4];
  __shared__ float scsh;
  if (lane == 0) red[wid] = ss;
  __syncthreads();
  if (tid == 0) scsh = rsqrtf((red[0] + red[1] + red[2] + red[3]) * (1.f / H_) + EPS_);
  __syncthreads();
  float sc = scsh;
#pragma unroll
  for (int i = 0; i < 4; i++) {
    int c = i * 256 + tid;
    float nv = v[i] * sc * w[c];
    if (sum_out) sum_out[(size_t)t * H_ + c] = v[i];
    if (nrm_out) nrm_out[(size_t)t * H_ + c] = nv;
    if (nrm_bf)  nrm_bf[(size_t)t * H_ + c] = f2bf(nv);
  }
}

// ---------------- bf16 MFMA GEMM core: C[128x128] = A_gather[128xK] @ B[:,K]^T --------
__device__ __forceinline__ void mfma_core(const short* __restrict__ A, int lda,
                                          const short* __restrict__ B, int ldb,
                                          int n0, int K,
                                          const int* rows_sh, char* smem,
                                          f32x4 acc[4][4]) {
  const int tid = threadIdx.x;
  const int wid = tid >> 6, lane = tid & 63;
  const int wr = wid >> 1, wc = wid & 1;
  const int fl = lane & 15, fh = lane >> 4;
  const short* src[4];
  unsigned lofs[4];
  {
    const int kofs = (lane & 3) * 8;
    const int r4 = lane >> 2;
#pragma unroll
    for (int j = 0; j < 4; j++) {
      int inst = (wid & 1) * 4 + j;
      int row = inst * 16 + r4;
      if (wid < 2) {
        src[j] = A + (size_t)rows_sh[row] * lda + kofs;
        lofs[j] = inst * 1024u;
      } else {
        src[j] = B + (size_t)(n0 + row) * ldb + kofs;
        lofs[j] = 8192u + inst * 1024u;
      }
    }
  }
  char* As = smem;
  char* Bs = smem + 8192;
  const int abase = (wr * 64 + fl) * 64 + fh * 16;
  const int bbase = (wc * 64 + fl) * 64 + fh * 16;
  for (int kt = 0; kt < K; kt += 32) {
#pragma unroll
    for (int j = 0; j < 4; j++) gload_lds16(src[j] + kt, smem + lofs[j]);
    asm volatile("s_waitcnt vmcnt(0)" ::: "memory");
    __syncthreads();
    short8 a[4], b[4];
#pragma unroll
    for (int mi = 0; mi < 4; mi++) a[mi] = *(const short8*)(As + abase + mi * 1024);
#pragma unroll
    for (int nj = 0; nj < 4; nj++) b[nj] = *(const short8*)(Bs + bbase + nj * 1024);
#pragma unroll
    for (int mi = 0; mi < 4; mi++)
#pragma unroll
      for (int nj = 0; nj < 4; nj++)
        acc[mi][nj] = __builtin_amdgcn_mfma_f32_16x16x32_bf16(a[mi], b[nj], acc[mi][nj], 0, 0, 0);
    __syncthreads();
  }
}

// ---------------- QKV projection ----------------
__global__ __launch_bounds__(256) void k_mfma_qkv(const short* __restrict__ A,
                                                  const short* __restrict__ W,
                                                  const float* __restrict__ bias,
                                                  float* __restrict__ out) {
  __shared__ __align__(16) char smem[16384];
  __shared__ int rows_sh[128];
  int m0 = blockIdx.y * 128, n0 = blockIdx.x * 128;
  int tid = threadIdx.x;
  if (tid < 128) rows_sh[tid] = m0 + tid;
  __syncthreads();
  f32x4 acc[4][4] = {};
  mfma_core(A, H_, W, H_, n0, H_, rows_sh, smem, acc);
  const int wid = tid >> 6, lane = tid & 63;
  const int wr = wid >> 1, wc = wid & 1, fl = lane & 15, fh = lane >> 4;
#pragma unroll
  for (int mi = 0; mi < 4; mi++)
#pragma unroll
    for (int nj = 0; nj < 4; nj++) {
      int c = n0 + wc * 64 + nj * 16 + fl;
      float bv = bias[c];
#pragma unroll
      for (int j = 0; j < 4; j++) {
        int r = m0 + wr * 64 + mi * 16 + fh * 4 + j;
        out[(size_t)r * QKV_ + c] = acc[mi][nj][j] + bv;
      }
    }
}

// ---------------- O projection + bias + residual -> res2 ----------------
__global__ __launch_bounds__(256) void k_mfma_o(const short* __restrict__ A,
                                                const short* __restrict__ W,
                                                const float* __restrict__ bias,
                                                const float* __restrict__ res1,
                                                float* __restrict__ res2) {
  __shared__ __align__(16) char smem[16384];
  __shared__ int rows_sh[128];
  int m0 = blockIdx.y * 128, n0 = blockIdx.x * 128;
  int tid = threadIdx.x;
  if (tid < 128) rows_sh[tid] = m0 + tid;
  __syncthreads();
  f32x4 acc[4][4] = {};
  mfma_core(A, H_, W, H_, n0, H_, rows_sh, smem, acc);
  const int wid = tid >> 6, lane = tid & 63;
  const int wr = wid >> 1, wc = wid & 1, fl = lane & 15, fh = lane >> 4;
#pragma unroll
  for (int mi = 0; mi < 4; mi++)
#pragma unroll
    for (int nj = 0; nj < 4; nj++) {
      int c = n0 + wc * 64 + nj * 16 + fl;
      float bv = bias[c];
#pragma unroll
      for (int j = 0; j < 4; j++) {
        int r = m0 + wr * 64 + mi * 16 + fh * 4 + j;
        res2[(size_t)r * H_ + c] = acc[mi][nj][j] + bv + res1[(size_t)r * H_ + c];
      }
    }
}

// ---------------- RoPE + bf16 emit: qb (scaled by D^-1/2), kb ----------------
__global__ void k_rope_cvt(const float* __restrict__ qkv, const int* __restrict__ positions,
                           short* __restrict__ qb, short* __restrict__ kb) {
  int idx = blockIdx.x * 256 + threadIdx.x;  // S * 20 heads * 32 pairs
  int i = idx & 31;
  int hd = (idx >> 5) % 20;
  int t = idx / (20 * 32);
  const float* base = qkv + (size_t)t * QKV_ + (hd < NH_ ? hd * D_ : NH_ * D_ + (hd - NH_) * D_);
  float pos = (float)positions[t];
  float invf = powf(10000.f, -(float)i * (1.f / 32.f));
  float ang = pos * invf;
  float sn, cs;
  sincosf(ang, &sn, &cs);
  float x1 = base[i], x2 = base[i + 32];
  float r1 = x1 * cs - x2 * sn;
  float r2 = x2 * cs + x1 * sn;
  if (hd < NH_) {
    short* o = qb + (size_t)t * H_ + hd * D_;
    o[i]      = f2bf(r1 * 0.125f);   // fold D^-0.5 into Q
    o[i + 32] = f2bf(r2 * 0.125f);
  } else {
    short* o = kb + (size_t)t * (NKV_ * D_) + (hd - NH_) * D_;
    o[i]      = f2bf(r1);
    o[i + 32] = f2bf(r2);
  }
}

// ---------------- V transpose to d-major bf16: vbT[kvh][d][t] ----------------
__global__ __launch_bounds__(256) void k_vcvt(const float* __restrict__ qkv,
                                              short* __restrict__ vbT) {
  int id = blockIdx.x * 256 + threadIdx.x;  // NKV*D*S
  int t = id & (S_ - 1);
  int rest = id >> 11;
  int d = rest & 63;
  int kvh = rest >> 6;
  vbT[id] = f2bf(qkv[(size_t)t * QKV_ + (NH_ + NKV_) * D_ + kvh * D_ + d]);
}

// ---------------- MFMA flash attention with sink ----------------
// grid (16, NH): block x handles q-tiles x and 31-x (paired for load balance).
// 4 waves, each owns 16 q-rows. KV chunk = 64 keys.
__global__ __launch_bounds__(256) void k_attn_mfma(const short* __restrict__ qb,
                                                   const short* __restrict__ kb,
                                                   const short* __restrict__ vbT,
                                                   const float* __restrict__ sinks,
                                                   short* __restrict__ attnb) {
  const int h = blockIdx.y;
  const int kvh = h >> 2;
  const int tid = threadIdx.x;
  const int wid = tid >> 6, lane = tid & 63;
  const int fl = lane & 15, fh = lane >> 4;

  __shared__ __align__(16) short Ks[64 * 64];   // [key][d], XOR-swizzled cols
  __shared__ __align__(16) short Vts[64 * 64];  // [d][key], XOR-swizzled cols
  __shared__ short Pl[4][16][72];               // per-wave P, padded rows

  const float snk = sinks[h];
  // staging source lane permutation (inverse swizzle): 16B segment s of row r
  // comes from global byte 16*(s ^ (r&7))
  const int srcoff = 8 * ((lane & 7) ^ (lane >> 3));  // in shorts
  const int srow = lane >> 3;                         // row-within-8

#pragma unroll
  for (int rep = 0; rep < 2; rep++) {
    const int qt = rep == 0 ? blockIdx.x : 31 - blockIdx.x;
    const int qbase = qt * 64;
    const int qrow = qbase + wid * 16 + fl;
    short8 qa[2];
#pragma unroll
    for (int p = 0; p < 2; p++)
      qa[p] = *(const short8*)(qb + (size_t)qrow * H_ + h * 64 + p * 32 + fh * 8);

    float mreg[4], lreg[4];
    f32x4 oacc[4] = {};
#pragma unroll
    for (int j = 0; j < 4; j++) { mreg[j] = -1e30f; lreg[j] = 0.f; }

    for (int kc = 0; kc <= qt; kc++) {
      // ---- stage K tile + Vt tile (8 gload insts each, 2 per wave) ----
#pragma unroll
      for (int ii = 0; ii < 2; ii++) {
        int inst = wid * 2 + ii;
        int krow = kc * 64 + inst * 8 + srow;
        gload_lds16(kb + (size_t)krow * (NKV_ * D_) + kvh * D_ + srcoff,
                    (char*)Ks + inst * 1024);
        int drow = inst * 8 + srow;
        gload_lds16(vbT + (size_t)(kvh * 64 + drow) * S_ + kc * 64 + srcoff,
                    (char*)Vts + inst * 1024);
      }
      asm volatile("s_waitcnt vmcnt(0)" ::: "memory");
      __syncthreads();

      // ---- QK^T: 4 key-tiles x (D=64 -> 2 mfma) ----
      f32x4 sacc[4] = {};
#pragma unroll
      for (int p = 0; p < 2; p++) {
        const int cswz_base = (p * 4 + fh);
#pragma unroll
        for (int t = 0; t < 4; t++) {
          int r = t * 16 + fl;
          short8 kf = *(const short8*)((const char*)Ks + r * 128 + 16 * (cswz_base ^ (fl & 7)));
          sacc[t] = __builtin_amdgcn_mfma_f32_16x16x32_bf16(qa[p], kf, sacc[t], 0, 0, 0);
        }
      }
      // ---- causal mask (diagonal chunk only) ----
      if (kc == qt) {
#pragma unroll
        for (int t = 0; t < 4; t++) {
          int key = kc * 64 + t * 16 + fl;
#pragma unroll
          for (int j = 0; j < 4; j++) {
            int q = qbase + wid * 16 + fh * 4 + j;
            if (key > q) sacc[t][j] = -1e30f;
          }
        }
      }
      // ---- online softmax (wave-parallel, 16-lane groups) ----
#pragma unroll
      for (int j = 0; j < 4; j++) {
        float vm = fmaxf(fmaxf(sacc[0][j], sacc[1][j]), fmaxf(sacc[2][j], sacc[3][j]));
        vm = fmaxf(vm, __shfl_xor(vm, 1));
        vm = fmaxf(vm, __shfl_xor(vm, 2));
        vm = fmaxf(vm, __shfl_xor(vm, 4));
        vm = fmaxf(vm, __shfl_xor(vm, 8));
        float mn = fmaxf(mreg[j], vm);
        float sf = __expf(mreg[j] - mn);
        float ps = 0.f;
#pragma unroll
        for (int t = 0; t < 4; t++) {
          float pv = __expf(sacc[t][j] - mn);
          ps += pv;
          Pl[wid][fh * 4 + j][t * 16 + fl] = f2bf(pv);
        }
        ps += __shfl_xor(ps, 1);
        ps += __shfl_xor(ps, 2);
        ps += __shfl_xor(ps, 4);
        ps += __shfl_xor(ps, 8);
        lreg[j] = lreg[j] * sf + ps;
        mreg[j] = mn;
#pragma unroll
        for (int u = 0; u < 4; u++) oacc[u][j] *= sf;
      }
      // ---- PV: A = P (LDS round-trip), B = Vt ----
#pragma unroll
      for (int p = 0; p < 2; p++) {
        short8 pa = *(const short8*)((const char*)&Pl[wid][0][0] + fl * 144 + p * 64 + fh * 16);
        const int cswz_base = (p * 4 + fh);
#pragma unroll
        for (int u = 0; u < 4; u++) {
          int r = u * 16 + fl;
          short8 vf = *(const short8*)((const char*)Vts + r * 128 + 16 * (cswz_base ^ (fl & 7)));
          oacc[u] = __builtin_amdgcn_mfma_f32_16x16x32_bf16(pa, vf, oacc[u], 0, 0, 0);
        }
      }
      __syncthreads();
    }
    // ---- epilogue: sink + normalize, write bf16 ----
#pragma unroll
    for (int j = 0; j < 4; j++) {
      float mf = fmaxf(mreg[j], snk);
      float denom = lreg[j] * __expf(mreg[j] - mf) + __expf(snk - mf);
      float osc = __expf(mreg[j] - mf) / denom;
      int q = qbase + wid * 16 + fh * 4 + j;
#pragma unroll
      for (int u = 0; u < 4; u++)
        attnb[(size_t)q * H_ + h * 64 + u * 16 + fl] = f2bf(oacc[u][j] * osc);
    }
  }
}

// ---------------- router (fp32 h2) ----------------
__global__ __launch_bounds__(64) void k_router(const float* __restrict__ h2,
                                               const float* __restrict__ rw,
                                               const float* __restrict__ rb,
                                               int* __restrict__ counts,
                                               int* __restrict__ perm,
                                               float* __restrict__ pw) {
  int t = blockIdx.x, lane = threadIdx.x;
  float acc[E_];
#pragma unroll
  for (int e = 0; e < E_; e++) acc[e] = 0.f;
  for (int i = 0; i < 16; i++) {
    float x = h2[(size_t)t * H_ + i * 64 + lane];
#pragma unroll
    for (int e = 0; e < E_; e++) acc[e] += x * rw[e * H_ + i * 64 + lane];
  }
#pragma unroll
  for (int e = 0; e < E_; e++) {
#pragma unroll
    for (int off = 32; off > 0; off >>= 1) acc[e] += __shfl_xor(acc[e], off);
  }
  if (lane == 0) {
    float lg[E_];
#pragma unroll
    for (int e = 0; e < E_; e++) lg[e] = acc[e] + rb[e];
    int i0 = 0;
    float v0 = lg[0];
    for (int e = 1; e < E_; e++)
      if (lg[e] > v0) { v0 = lg[e]; i0 = e; }
    int i1 = -1;
    float v1 = -INFINITY;
    for (int e = 0; e < E_; e++) {
      if (e == i0) continue;
      if (lg[e] > v1) { v1 = lg[e]; i1 = e; }
    }
    float ex = expf(v1 - v0);
    float w0 = 1.f / (1.f + ex);
    float w1 = ex * w0;
    int p0 = atomicAdd(&counts[i0], 1);
    if (p0 < S_) { perm[i0 * S_ + p0] = t * 2;     pw[i0 * S_ + p0] = w0; }
    int p1 = atomicAdd(&counts[i1], 1);
    if (p1 < S_) { perm[i1 * S_ + p1] = t * 2 + 1; pw[i1 * S_ + p1] = w1; }
  }
}

// ---------------- MoE gate_up + SwiGLU -> actbuf (bf16, slot-indexed) ----------------
__global__ __launch_bounds__(256) void k_mfma_gu(const short* __restrict__ h2b,
                                                 const short* __restrict__ W,
                                                 const float* __restrict__ gu_b,
                                                 const int* __restrict__ counts,
                                                 const int* __restrict__ perm,
                                                 short* __restrict__ actb) {
  int e = blockIdx.z;
  int cnt = counts[e];
  if (cnt < 0) cnt = 0;
  if (cnt > S_) cnt = S_;
  int m0 = blockIdx.y * 128;
  if (m0 >= cnt) return;
  int n0 = blockIdx.x * 128;
  __shared__ __align__(16) char smem[16384];
  __shared__ int rows_sh[128];
  __shared__ int slots_sh[128];
  int tid = threadIdx.x;
  if (tid < 128) {
    int idx = m0 + tid;
    int p = (idx < cnt) ? perm[e * S_ + idx] : -1;
    if (p < 0 || p >= 2 * S_) p = -1;
    slots_sh[tid] = p;
    rows_sh[tid] = (p >= 0) ? (p >> 1) : 0;
  }
  __syncthreads();
  f32x4 acc[4][4] = {};
  mfma_core(h2b, H_, W + (size_t)e * 2 * F_ * H_, H_, n0, H_, rows_sh, smem, acc);
  const int wid = tid >> 6, lane = tid & 63;
  const int wr = wid >> 1, wc = wid & 1, fl = lane & 15, fh = lane >> 4;
  const float* gub = gu_b + (size_t)e * 2 * F_;
#pragma unroll
  for (int mi = 0; mi < 4; mi++)
#pragma unroll
    for (int nj = 0; nj < 4; nj++) {
      int c = n0 + wc * 64 + nj * 16 + fl;
      float bv = gub[c];
#pragma unroll
      for (int j = 0; j < 4; j++) {
        int r = wr * 64 + mi * 16 + fh * 4 + j;
        float v = acc[mi][nj][j] + bv;
        float other = __shfl_xor(v, 1);
        if (!(lane & 1)) {
          int slot = slots_sh[r];
          if (slot >= 0) {
            float g = fminf(v, LIMIT_);
            float u = fminf(fmaxf(other, -LIMIT_), LIMIT_);
            float a = (u + 1.f) * (g / (1.f + expf(-g * ALPHA_)));
            actb[(size_t)slot * F_ + (c >> 1)] = f2bf(a);
          }
        }
      }
    }
}

// ---------------- MoE down proj -> dnout (fp32, slot-indexed, weight applied) ---------
__global__ __launch_bounds__(256) void k_mfma_down(const short* __restrict__ actb,
                                                   const short* __restrict__ W,
                                                   const float* __restrict__ dn_b,
                                                   const int* __restrict__ counts,
                                                   const int* __restrict__ perm,
                                                   const float* __restrict__ pw,
                                                   float* __restrict__ dnout) {
  int e = blockIdx.z;
  int cnt = counts[e];
  if (cnt < 0) cnt = 0;
  if (cnt > S_) cnt = S_;
  int m0 = blockIdx.y * 128;
  if (m0 >= cnt) return;
  int n0 = blockIdx.x * 128;
  __shared__ __align__(16) char smem[16384];
  __shared__ int rows_sh[128];
  __shared__ float wts_sh[128];
  int tid = threadIdx.x;
  if (tid < 128) {
    int idx = m0 + tid;
    int p = 0;
    float w = 0.f;
    if (idx < cnt) { p = perm[e * S_ + idx]; w = pw[e * S_ + idx]; }
    if (p < 0 || p >= 2 * S_) { p = 0; w = 0.f; }
    rows_sh[tid] = p;  // actbuf is slot-indexed
    wts_sh[tid] = w;
  }
  __syncthreads();
  f32x4 acc[4][4] = {};
  mfma_core(actb, F_, rows_sh == nullptr ? actb : (W + (size_t)e * H_ * F_), F_, n0, F_, rows_sh, smem, acc);
  const int wid = tid >> 6, lane = tid & 63;
  const int wr = wid >> 1, wc = wid & 1, fl = lane & 15, fh = lane >> 4;
  const float* dnb = dn_b + (size_t)e * H_;
#pragma unroll
  for (int mi = 0; mi < 4; mi++)
#pragma unroll
    for (int nj = 0; nj < 4; nj++) {
      int c = n0 + wc * 64 + nj * 16 + fl;
      float bv = dnb[c];
#pragma unroll
      for (int j = 0; j < 4; j++) {
        int r = wr * 64 + mi * 16 + fh * 4 + j;
        if (m0 + r < cnt) {
          int slot = rows_sh[r];
          dnout[(size_t)slot * H_ + c] = (acc[mi][nj][j] + bv) * wts_sh[r];
        }
      }
    }
}

// ---------------- combine the two expert slots per token ----------------
__global__ __launch_bounds__(256) void k_combine(const float* __restrict__ dnout,
                                                 float* __restrict__ out) {
  int i = blockIdx.x * 256 + threadIdx.x;  // over S*H/4
  int t = i >> 8, c = i & 255;             // H/4 = 256
  const float4* a = (const float4*)dnout;
  float4 x = a[(size_t)(2 * t) * 256 + c];
  float4 y = a[(size_t)(2 * t + 1) * 256 + c];
  float4 o;
  o.x = x.x + y.x; o.y = x.y + y.y; o.z = x.z + y.z; o.w = x.w + y.w;
  ((float4*)out)[i] = o;
}

extern "C" void kernel_launch(void* const* d_in, const int* in_sizes, int n_in,
                              void* d_out, int out_size, void* d_ws, size_t ws_size,
                              hipStream_t stream) {
  (void)in_sizes; (void)n_in; (void)out_size; (void)ws_size;
  const float* hidden   = (const float*)d_in[0];
  const float* residual = (const float*)d_in[1];
  const int*   positions= (const int*)d_in[2];
  const float* ln1_w    = (const float*)d_in[3];
  const float* ln2_w    = (const float*)d_in[4];
  const float* qkv_w    = (const float*)d_in[5];
  const float* qkv_b    = (const float*)d_in[6];
  const float* sinks    = (const float*)d_in[7];
  const float* o_w      = (const float*)d_in[8];
  const float* o_b      = (const float*)d_in[9];
  const float* router_w = (const float*)d_in[10];
  const float* router_b = (const float*)d_in[11];
  const float* gu_w     = (const float*)d_in[12];
  const float* gu_b     = (const float*)d_in[13];
  const float* dn_w     = (const float*)d_in[14];
  const float* dn_b     = (const float*)d_in[15];

  float* out_moe = (float*)d_out;
  float* res2 = (float*)d_out + (size_t)S_ * H_;

  char* ws = (char*)d_ws;
  size_t off = 0;
  auto alloc = [&](size_t bytes) {
    void* p = ws + off;
    off = (off + bytes + 255) & ~(size_t)255;
    return p;
  };
  int*   counts  = (int*)alloc(E_ * sizeof(int));
  int*   perm    = (int*)alloc((size_t)E_ * S_ * sizeof(int));
  float* pw      = (float*)alloc((size_t)E_ * S_ * sizeof(float));
  float* res1    = (float*)alloc((size_t)S_ * H_ * 4);
  short* hbuf_b  = (short*)alloc((size_t)S_ * H_ * 2);
  float* qkv     = (float*)alloc((size_t)S_ * QKV_ * 4);
  short* qb      = (short*)alloc((size_t)S_ * H_ * 2);
  short* kb      = (short*)alloc((size_t)S_ * NKV_ * D_ * 2);
  short* vbT     = (short*)alloc((size_t)S_ * NKV_ * D_ * 2);
  short* attnb   = (short*)alloc((size_t)S_ * H_ * 2);
  float* h2      = (float*)alloc((size_t)S_ * H_ * 4);
  short* h2b     = (short*)alloc((size_t)S_ * H_ * 2);
  short* actb    = (short*)alloc((size_t)2 * S_ * F_ * 2);
  float* dnout   = (float*)alloc((size_t)2 * S_ * H_ * 4);
  short* qkv_wb  = (short*)alloc((size_t)QKV_ * H_ * 2);
  short* o_wb    = (short*)alloc((size_t)H_ * H_ * 2);
  short* gu_wb   = (short*)alloc((size_t)E_ * 2 * F_ * H_ * 2);
  short* dn_wb   = (short*)alloc((size_t)E_ * H_ * F_ * 2);

  hipMemsetAsync(counts, 0, E_ * sizeof(int), stream);

  k_cvt<<<1024, 256, 0, stream>>>(qkv_w, qkv_wb, QKV_ * H_ / 4);
  k_cvt<<<1024, 256, 0, stream>>>(o_w, o_wb, H_ * H_ / 4);
  k_cvt<<<2048, 256, 0, stream>>>(gu_w, gu_wb, E_ * 2 * F_ * H_ / 4);
  k_cvt<<<2048, 256, 0, stream>>>(dn_w, dn_wb, E_ * H_ * F_ / 4);

  k_norm<<<S_, 256, 0, stream>>>(hidden, residual, ln1_w, res1, nullptr, hbuf_b);
  k_mfma_qkv<<<dim3(QKV_ / 128, S_ / 128), 256, 0, stream>>>(hbuf_b, qkv_wb, qkv_b, qkv);
  k_rope_cvt<<<(S_ * 20 * 32) / 256, 256, 0, stream>>>(qkv, positions, qb, kb);
  k_vcvt<<<(S_ * NKV_ * D_) / 256, 256, 0, stream>>>(qkv, vbT);
  k_attn_mfma<<<dim3(16, NH_), 256, 0, stream>>>(qb, kb, vbT, sinks, attnb);
  k_mfma_o<<<dim3(H_ / 128, S_ / 128), 256, 0, stream>>>(attnb, o_wb, o_b, res1, res2);
  k_norm<<<S_, 256, 0, stream>>>(res2, nullptr, ln2_w, nullptr, h2, h2b);
  k_router<<<S_, 64, 0, stream>>>(h2, router_w, router_b, counts, perm, pw);
  k_mfma_gu<<<dim3(2 * F_ / 128, S_ / 128, E_), 256, 0, stream>>>(h2b, gu_wb, gu_b, counts, perm, actb);
  k_mfma_down<<<dim3(H_ / 128, S_ / 128, E_), 256, 0, stream>>>(actb, dn_wb, dn_b, counts, perm, pw, dnout);
  k_combine<<<(S_ * H_ / 4) / 256, 256, 0, stream>>>(dnout, out_moe);
}